// Round 16
// baseline (791.819 us; speedup 1.0000x reference)
//
#include <hip/hip_runtime.h>
#include <stdint.h>

#define SEQ 2048
#define HID 4096
#define KVHID 1024
#define NHEAD 32
#define DHEAD 128
#define HEAVY 204
#define SEL_N 1844

typedef float f32x4 __attribute__((ext_vector_type(4)));
typedef __bf16 bf16x8 __attribute__((ext_vector_type(8)));

#define MFMA16 __builtin_amdgcn_mfma_f32_16x16x32_bf16

__device__ __forceinline__ unsigned short f2bf(float x) {
    unsigned int u = __float_as_uint(x);
    u = (u + 0x7fffu + ((u >> 16) & 1u)) >> 16;
    return (unsigned short)u;
}
__device__ __forceinline__ float bf2f(unsigned short s) {
    return __uint_as_float(((unsigned int)s) << 16);
}
__device__ __forceinline__ unsigned long long pack4(unsigned short a, unsigned short b,
                                                    unsigned short c, unsigned short d) {
    return (unsigned long long)a | ((unsigned long long)b << 16) |
           ((unsigned long long)c << 32) | ((unsigned long long)d << 48);
}
__device__ __forceinline__ float fexp2(float x) {
#if __has_builtin(__builtin_amdgcn_exp2f)
    return __builtin_amdgcn_exp2f(x);
#else
    float r; asm volatile("v_exp_f32 %0, %1\ns_nop 1" : "=v"(r) : "v"(x)); return r;
#endif
}
__device__ __forceinline__ unsigned cvt_pk_bf16(float lo, float hi) {
    unsigned r; asm("v_cvt_pk_bf16_f32 %0, %1, %2" : "=v"(r) : "v"(lo), "v"(hi)); return r;
}
__device__ __forceinline__ void gload_lds16(const unsigned short* g, unsigned short* l) {
    __builtin_amdgcn_global_load_lds(
        (const __attribute__((address_space(1))) void*)g,
        (__attribute__((address_space(3))) void*)l, 16, 0, 0);
}
__device__ __forceinline__ void block_sync() {
    asm volatile("" ::: "memory");
    __builtin_amdgcn_s_barrier();
    asm volatile("" ::: "memory");
}

// ---------------------------------------------------------------------------
// Merged prep kernel.
//   [0,2048):      split hidden fp32 -> bf16 hi/lo
//   [2048,6144):   Wq -> WqT hi/lo
//   [6144,7168):   Wk -> WkT hi/lo
//   [7168,8192):   Wv -> WvT (plain)
//   [8192,8256):   zero colsum
//   [8256,12352):  Wo -> WoT (plain; only launched when ws is big enough)
// ---------------------------------------------------------------------------
template<bool SPLIT>
__device__ __forceinline__ void wprep_body(const float* __restrict__ W,
    unsigned short* __restrict__ Thi, unsigned short* __restrict__ Tlo,
    int K, int N, int bx, int by, float (*T)[65])
{
    const int k0 = by << 6, n0 = bx << 6;
    const int tid = threadIdx.x;
    const int c = tid & 63, r4 = tid >> 6;
    #pragma unroll
    for (int i = 0; i < 16; ++i)
        T[r4 + i * 4][c] = W[(size_t)(k0 + r4 + i * 4) * N + n0 + c];
    __syncthreads();
    #pragma unroll
    for (int i = 0; i < 16; ++i) {
        const int n = r4 + i * 4;
        const float x = T[c][n];
        const size_t o = (size_t)(n0 + n) * K + k0 + c;
        const unsigned short h = f2bf(x);
        Thi[o] = h;
        if constexpr (SPLIT) Tlo[o] = f2bf(x - bf2f(h));
    }
}

__global__ __launch_bounds__(256) void prep_all(
    const float* __restrict__ hidden,
    unsigned short* __restrict__ hs_hi, unsigned short* __restrict__ hs_lo,
    const float* __restrict__ Wq, unsigned short* __restrict__ wqT_hi,
    unsigned short* __restrict__ wqT_lo,
    const float* __restrict__ Wk, unsigned short* __restrict__ wkT_hi,
    unsigned short* __restrict__ wkT_lo,
    const float* __restrict__ Wv, unsigned short* __restrict__ wvT,
    double* __restrict__ colsum,
    const float* __restrict__ Wo, unsigned short* __restrict__ woT)
{
    __shared__ float T[64][65];
    const int bid = blockIdx.x;
    if (bid < 2048) {
        const int n4 = (SEQ * HID) / 4;
        int i = bid * 256 + threadIdx.x;
        for (; i < n4; i += 2048 * 256) {
            const float4 v = ((const float4*)hidden)[i];
            const unsigned short h0 = f2bf(v.x), h1 = f2bf(v.y),
                                 h2 = f2bf(v.z), h3 = f2bf(v.w);
            ((unsigned long long*)hs_hi)[i] = pack4(h0, h1, h2, h3);
            ((unsigned long long*)hs_lo)[i] =
                pack4(f2bf(v.x - bf2f(h0)), f2bf(v.y - bf2f(h1)),
                      f2bf(v.z - bf2f(h2)), f2bf(v.w - bf2f(h3)));
        }
    } else if (bid < 6144) {
        const int idx = bid - 2048;
        wprep_body<true>(Wq, wqT_hi, wqT_lo, HID, HID, idx & 63, idx >> 6, T);
    } else if (bid < 7168) {
        const int idx = bid - 6144;
        wprep_body<true>(Wk, wkT_hi, wkT_lo, HID, KVHID, idx & 15, idx >> 4, T);
    } else if (bid < 8192) {
        const int idx = bid - 7168;
        wprep_body<false>(Wv, wvT, nullptr, HID, KVHID, idx & 15, idx >> 4, T);
    } else if (bid < 8256) {
        // zero colsum (NHEAD*SEQ doubles)
        unsigned long long* p = (unsigned long long*)colsum;
        const int n = NHEAD * SEQ;
        for (int i = (bid - 8192) * 256 + threadIdx.x; i < n; i += 64 * 256)
            p[i] = 0ull;
    } else {
        const int idx = bid - 8256;
        wprep_body<false>(Wo, woT, nullptr, HID, HID, idx & 63, idx >> 6, T);
    }
}

// ---------------------------------------------------------------------------
// Standalone wprep (fallback for Wo when ws too small; aliases wqT_hi).
// ---------------------------------------------------------------------------
template<bool SPLIT>
__global__ __launch_bounds__(256) void wprep(const float* __restrict__ W,
    unsigned short* __restrict__ Thi, unsigned short* __restrict__ Tlo, int K, int N)
{
    __shared__ float T[64][65];
    wprep_body<SPLIT>(W, Thi, Tlo, K, N, blockIdx.x, blockIdx.y, T);
}

// ---------------------------------------------------------------------------
// GEMM device body: SPLIT = 2-buffer double-barrier; non-SPLIT = 4-buffer
// rotation, 2-deep prefetch, one barrier per K-step. sm = 64KB.
// ---------------------------------------------------------------------------
template<bool SPLIT, int OUTMODE /*0=bf16,1=f32,2=bf16 hi+lo*/, bool BIAS>
__device__ __forceinline__ void gemm_body(
    const unsigned short* __restrict__ Ahi, const unsigned short* __restrict__ Alo,
    const unsigned short* __restrict__ Bhi, const unsigned short* __restrict__ Blo,
    const float* __restrict__ bias,
    void* __restrict__ C0, unsigned short* __restrict__ C1,
    int M, int N, int K, int mb, int nb, unsigned short* sm)
{
    constexpr int NT = SPLIT ? 4 : 2;
    const int tid = threadIdx.x;
    const int l = tid & 63, w = tid >> 6;
    const int lr = l & 15, lg = l >> 4;
    const int wm = (w >> 1) * 64, wn = (w & 1) * 64;
    const int m0 = mb * 128, n0 = nb * 128;

    const unsigned short* aH = Ahi + (size_t)m0 * K;
    const unsigned short* bH = Bhi + (size_t)n0 * K;
    const unsigned short* aL = SPLIT ? Alo + (size_t)m0 * K : nullptr;
    const unsigned short* bL = SPLIT ? Blo + (size_t)n0 * K : nullptr;

    const int s0_ = tid, s1_ = tid + 256;
    const int r0_ = s0_ >> 2, c0_ = (s0_ & 3) ^ (r0_ & 3);
    const int r1_ = s1_ >> 2, c1_ = (s1_ & 3) ^ (r1_ & 3);
    const size_t g0off = (size_t)r0_ * K + c0_ * 8;
    const size_t g1off = (size_t)r1_ * K + c1_ * 8;

#define GB_SLOT(buf, t) (sm + ((buf) * NT + (t)) * 4096)
#define GB_STAGE(buf, kk)                                                       \
    do {                                                                        \
        const int k0s = (kk) << 5;                                              \
        gload_lds16(aH + g0off + k0s, GB_SLOT(buf, 0) + s0_ * 8);               \
        gload_lds16(aH + g1off + k0s, GB_SLOT(buf, 0) + s1_ * 8);               \
        gload_lds16(bH + g0off + k0s, GB_SLOT(buf, 1) + s0_ * 8);               \
        gload_lds16(bH + g1off + k0s, GB_SLOT(buf, 1) + s1_ * 8);               \
        if constexpr (SPLIT) {                                                  \
            gload_lds16(aL + g0off + k0s, GB_SLOT(buf, 2) + s0_ * 8);           \
            gload_lds16(aL + g1off + k0s, GB_SLOT(buf, 2) + s1_ * 8);           \
            gload_lds16(bL + g0off + k0s, GB_SLOT(buf, 3) + s0_ * 8);           \
            gload_lds16(bL + g1off + k0s, GB_SLOT(buf, 3) + s1_ * 8);           \
        }                                                                       \
    } while (0)

#define GB_COMPUTE(BC)                                                          \
    do {                                                                        \
        bf16x8 ah[4], bh[4], al[4], bl[4];                                      \
        _Pragma("unroll")                                                       \
        for (int mi = 0; mi < 4; ++mi) {                                        \
            const int rr = wm + mi * 16 + lr;                                   \
            const int o = rr * 32 + ((lg ^ (rr & 3)) << 3);                     \
            ah[mi] = *(const bf16x8*)(GB_SLOT(BC, 0) + o);                      \
            if constexpr (SPLIT) al[mi] = *(const bf16x8*)(GB_SLOT(BC, 2) + o); \
        }                                                                       \
        _Pragma("unroll")                                                       \
        for (int ni = 0; ni < 4; ++ni) {                                        \
            const int rr = wn + ni * 16 + lr;                                   \
            const int o = rr * 32 + ((lg ^ (rr & 3)) << 3);                     \
            bh[ni] = *(const bf16x8*)(GB_SLOT(BC, 1) + o);                      \
            if constexpr (SPLIT) bl[ni] = *(const bf16x8*)(GB_SLOT(BC, 3) + o); \
        }                                                                       \
        __builtin_amdgcn_s_setprio(1);                                          \
        _Pragma("unroll")                                                       \
        for (int mi = 0; mi < 4; ++mi)                                          \
            _Pragma("unroll")                                                   \
            for (int ni = 0; ni < 4; ++ni) {                                    \
                acc[mi][ni] = MFMA16(ah[mi], bh[ni], acc[mi][ni], 0, 0, 0);     \
                if constexpr (SPLIT) {                                          \
                    acc[mi][ni] = MFMA16(ah[mi], bl[ni], acc[mi][ni], 0, 0, 0); \
                    acc[mi][ni] = MFMA16(al[mi], bh[ni], acc[mi][ni], 0, 0, 0); \
                }                                                               \
            }                                                                   \
        __builtin_amdgcn_s_setprio(0);                                          \
    } while (0)

    f32x4 acc[4][4];
    #pragma unroll
    for (int i = 0; i < 4; ++i)
        #pragma unroll
        for (int j = 0; j < 4; ++j) acc[i][j] = (f32x4){};

    const int nk = K >> 5;
    if constexpr (SPLIT) {
        GB_STAGE(0, 0);
        for (int kt = 0; kt < nk; ++kt) {
            if (kt + 1 < nk) {
                GB_STAGE((kt + 1) & 1, kt + 1);
                asm volatile("s_waitcnt vmcnt(8)" ::: "memory");
            } else {
                asm volatile("s_waitcnt vmcnt(0)" ::: "memory");
            }
            block_sync();
            GB_COMPUTE(kt & 1);
            block_sync();
        }
    } else {
        GB_STAGE(0, 0);
        GB_STAGE(1, 1);
        for (int kt = 0; kt < nk; ++kt) {
            if (kt + 2 < nk) {
                GB_STAGE((kt + 2) & 3, kt + 2);
                asm volatile("s_waitcnt vmcnt(8)" ::: "memory");
            } else if (kt + 1 < nk) {
                asm volatile("s_waitcnt vmcnt(4)" ::: "memory");
            } else {
                asm volatile("s_waitcnt vmcnt(0)" ::: "memory");
            }
            block_sync();
            GB_COMPUTE(kt & 3);
        }
    }
#undef GB_STAGE
#undef GB_COMPUTE
#undef GB_SLOT

    #pragma unroll
    for (int ni = 0; ni < 4; ++ni) {
        const int col = n0 + wn + ni * 16 + lr;
        float bv = 0.f;
        if constexpr (BIAS) bv = bias[col];
        #pragma unroll
        for (int mi = 0; mi < 4; ++mi) {
            #pragma unroll
            for (int r = 0; r < 4; ++r) {
                const int row = m0 + wm + mi * 16 + lg * 4 + r;
                const float x = acc[mi][ni][r] + bv;
                const size_t o = (size_t)row * N + col;
                if constexpr (OUTMODE == 1) {
                    ((float*)C0)[o] = x;
                } else if constexpr (OUTMODE == 0) {
                    ((unsigned short*)C0)[o] = f2bf(x);
                } else {
                    const unsigned short hi = f2bf(x);
                    ((unsigned short*)C0)[o] = hi;
                    C1[o] = f2bf(x - bf2f(hi));
                }
            }
        }
    }
}

// ---------------------------------------------------------------------------
// Merged Q/K/V projection (r15 mapping: 8x8 XCD rectangle for Q region).
// ---------------------------------------------------------------------------
__global__ __launch_bounds__(256) void qkv_gemm(
    const unsigned short* __restrict__ hs_hi, const unsigned short* __restrict__ hs_lo,
    const unsigned short* __restrict__ wqT_hi, const unsigned short* __restrict__ wqT_lo,
    const unsigned short* __restrict__ wkT_hi, const unsigned short* __restrict__ wkT_lo,
    const unsigned short* __restrict__ wvT,
    const float* __restrict__ bq, const float* __restrict__ bk, const float* __restrict__ bv,
    unsigned short* __restrict__ q_hi, unsigned short* __restrict__ q_lo,
    unsigned short* __restrict__ k_hi, unsigned short* __restrict__ k_lo,
    unsigned short* __restrict__ v_bf)
{
    __shared__ unsigned short sm[8 * 4096];   // 64KB
    const int bid = blockIdx.x;
    if (bid < 512) {
        const int r = bid & 7, rid = bid >> 3;
        const int mb = ((r >> 2) << 3) + (rid >> 3);
        const int nb = ((r & 3) << 3) + (rid & 7);
        gemm_body<true, 2, true>(hs_hi, hs_lo, wqT_hi, wqT_lo, bq, q_hi, q_lo,
                                 SEQ, HID, HID, mb, nb, sm);
    } else if (bid < 640) {
        const int idx = bid - 512;
        gemm_body<true, 2, true>(hs_hi, hs_lo, wkT_hi, wkT_lo, bk, k_hi, k_lo,
                                 SEQ, KVHID, HID, idx >> 3, idx & 7, sm);
    } else {
        const int idx = bid - 640;
        gemm_body<false, 0, true>(hs_hi, nullptr, wvT, nullptr, bv, v_bf, nullptr,
                                  SEQ, KVHID, HID, idx >> 3, idx & 7, sm);
    }
}

// ---------------------------------------------------------------------------
// Wo GEMM: plain bf16, f32 out, with the same 8x8 XCD rectangle swizzle
// (16 mb x 32 nb = 512 blocks, identical geometry to the Q region).
// ---------------------------------------------------------------------------
__global__ __launch_bounds__(256) void gemm_wo(
    const unsigned short* __restrict__ A, const unsigned short* __restrict__ B,
    float* __restrict__ C, int M, int N, int K)
{
    __shared__ unsigned short sm[8 * 4096];
    const int bid = blockIdx.x;
    const int r = bid & 7, rid = bid >> 3;
    const int mb = ((r >> 2) << 3) + (rid >> 3);
    const int nb = ((r & 3) << 3) + (rid & 7);
    gemm_body<false, 1, false>(A, nullptr, B, nullptr, nullptr, C, nullptr,
                               M, N, K, mb, nb, sm);
}

// ---------------------------------------------------------------------------
// V transpose: v[2048][1024] -> vT[1024][2048] (bf16).
// ---------------------------------------------------------------------------
__global__ __launch_bounds__(256) void transpose_v(const unsigned short* __restrict__ v,
                                                   unsigned short* __restrict__ vt)
{
    __shared__ unsigned short T[64][65];
    const int r0 = blockIdx.x * 64;
    const int c0 = blockIdx.y * 64;
    const int tid = threadIdx.x;
    const int cc = tid & 63, rr = tid >> 6;
    #pragma unroll
    for (int i = 0; i < 16; ++i)
        T[rr + i * 4][cc] = v[(size_t)(r0 + rr + i * 4) * KVHID + c0 + cc];
    __syncthreads();
    #pragma unroll
    for (int i = 0; i < 16; ++i) {
        const int oc = rr + i * 4;
        vt[(size_t)(c0 + oc) * SEQ + r0 + cc] = T[cc][oc];
    }
}

// ---------------------------------------------------------------------------
// Fused attention v8 (r13, unchanged).
// ---------------------------------------------------------------------------
__device__ __forceinline__ void stage_tile(
    const unsigned short* __restrict__ khi, const unsigned short* __restrict__ klo,
    unsigned short* kb, int kt, int kvoff, int w, int lane)
{
    const unsigned short* src = (w >> 1) ? klo : khi;
    unsigned short* dst = kb + (w >> 1) * 4096 + (w & 1) * 2048;
    const int lsub = lane >> 4;
    const int lbyte = (lane & 15) * 16;
    #pragma unroll
    for (int j = 0; j < 4; ++j) {
        const int row = (w & 1) * 16 + j * 4 + lsub;
        const int soff = (lbyte ^ ((row & 7) << 4)) >> 1;
        const unsigned short* g = src + (size_t)(kt * 32 + row) * KVHID + kvoff + soff;
        gload_lds16(g, dst + j * 512);
    }
}

__device__ __forceinline__ void process_qblock8(
    int head, int qb, int w, int lane,
    const unsigned short* __restrict__ qhi, const unsigned short* __restrict__ qlo,
    const unsigned short* __restrict__ khi, const unsigned short* __restrict__ klo,
    const unsigned short* __restrict__ vT,
    unsigned short* __restrict__ obuf, double* __restrict__ colsum,
    unsigned short* kbuf /*[4][8192]*/, unsigned short* pl)
{
    const int lr = lane & 15, lg = lane >> 4;
    const int kvoff = (head >> 2) * DHEAD;
    const int q0w = qb * 64 + w * 16;
    const int NT = 2 * qb + 2;
    const int wnt = ((q0w + 15) >> 5) + 1;
    const float C = 0.08838834764831845f * 1.44269504088896340f;

    bf16x8 qh[4], qlo4[4];
    {
        const size_t qbase = (size_t)(q0w + lr) * HID + head * DHEAD + lg * 8;
        #pragma unroll
        for (int s = 0; s < 4; ++s) {
            qh[s]   = *(const bf16x8*)(qhi + qbase + s * 32);
            qlo4[s] = *(const bf16x8*)(qlo + qbase + s * 32);
        }
    }
    const int swz = (lr & 7) << 3;

    float rl[4];
    // ================= sweep A: row sums =================
    {
        float lp[4] = {0.f, 0.f, 0.f, 0.f};
        stage_tile(khi, klo, kbuf, 0, kvoff, w, lane);
        stage_tile(khi, klo, kbuf + 8192, 1, kvoff, w, lane);
        for (int kt = 0; kt < NT; ++kt) {
            if (kt + 2 < NT) {
                stage_tile(khi, klo, kbuf + ((kt + 2) & 3) * 8192, kt + 2, kvoff, w, lane);
                asm volatile("s_waitcnt vmcnt(8)" ::: "memory");
            } else if (kt + 1 < NT) {
                asm volatile("s_waitcnt vmcnt(4)" ::: "memory");
            } else {
                asm volatile("s_waitcnt vmcnt(0)" ::: "memory");
            }
            block_sync();
            const unsigned short* kb = kbuf + (kt & 3) * 8192;
            if (kt < wnt) {
                f32x4 m0 = {}, m1 = {}, xa0 = {}, xb0 = {}, xa1 = {}, xb1 = {};
                #pragma unroll
                for (int s = 0; s < 4; ++s) {
                    const int d = s * 32 + lg * 8;
                    const bf16x8 k0h = *(const bf16x8*)(kb + (lr * 128 + (d ^ swz)));
                    const bf16x8 k1h = *(const bf16x8*)(kb + ((16 + lr) * 128 + (d ^ swz)));
                    const bf16x8 k0l = *(const bf16x8*)(kb + 4096 + lr * 128 + (d ^ swz));
                    const bf16x8 k1l = *(const bf16x8*)(kb + 4096 + (16 + lr) * 128 + (d ^ swz));
                    m0  = MFMA16(qh[s],   k0h, m0,  0, 0, 0);
                    m1  = MFMA16(qh[s],   k1h, m1,  0, 0, 0);
                    xa0 = MFMA16(qh[s],   k0l, xa0, 0, 0, 0);
                    xb0 = MFMA16(qlo4[s], k0h, xb0, 0, 0, 0);
                    xa1 = MFMA16(qh[s],   k1l, xa1, 0, 0, 0);
                    xb1 = MFMA16(qlo4[s], k1h, xb1, 0, 0, 0);
                }
                const bool full = (kt * 32 + 31 <= q0w);
                #pragma unroll
                for (int r = 0; r < 4; ++r) {
                    float e0 = fexp2((m0[r] + (xa0[r] + xb0[r])) * C);
                    float e1 = fexp2((m1[r] + (xa1[r] + xb1[r])) * C);
                    if (!full) {
                        const int q = q0w + lg * 4 + r;
                        if (kt * 32 + lr > q)      e0 = 0.f;
                        if (kt * 32 + 16 + lr > q) e1 = 0.f;
                    }
                    lp[r] += e0 + e1;
                }
            }
        }
        block_sync();
        #pragma unroll
        for (int r = 0; r < 4; ++r) {
            float v = lp[r];
            v += __shfl_xor(v, 1);
            v += __shfl_xor(v, 2);
            v += __shfl_xor(v, 4);
            v += __shfl_xor(v, 8);
            rl[r] = 1.0f / v;
        }
    }
    // ============ sweep B: p, colsum, PV =================
    {
        f32x4 oacc[8];
        #pragma unroll
        for (int f = 0; f < 8; ++f) oacc[f] = (f32x4){};
        stage_tile(khi, klo, kbuf, 0, kvoff, w, lane);
        stage_tile(khi, klo, kbuf + 8192, 1, kvoff, w, lane);
        for (int kt = 0; kt < NT; ++kt) {
            if (kt + 2 < NT) {
                stage_tile(khi, klo, kbuf + ((kt + 2) & 3) * 8192, kt + 2, kvoff, w, lane);
                asm volatile("s_waitcnt vmcnt(8)" ::: "memory");
            } else if (kt + 1 < NT) {
                asm volatile("s_waitcnt vmcnt(4)" ::: "memory");
            } else {
                asm volatile("s_waitcnt vmcnt(0)" ::: "memory");
            }
            block_sync();
            const unsigned short* kb = kbuf + (kt & 3) * 8192;
            if (kt < wnt) {
                f32x4 m0 = {}, m1 = {}, xa0 = {}, xb0 = {}, xa1 = {}, xb1 = {};
                #pragma unroll
                for (int s = 0; s < 4; ++s) {
                    const int d = s * 32 + lg * 8;
                    const bf16x8 k0h = *(const bf16x8*)(kb + (lr * 128 + (d ^ swz)));
                    const bf16x8 k1h = *(const bf16x8*)(kb + ((16 + lr) * 128 + (d ^ swz)));
                    const bf16x8 k0l = *(const bf16x8*)(kb + 4096 + lr * 128 + (d ^ swz));
                    const bf16x8 k1l = *(const bf16x8*)(kb + 4096 + (16 + lr) * 128 + (d ^ swz));
                    m0  = MFMA16(qh[s],   k0h, m0,  0, 0, 0);
                    m1  = MFMA16(qh[s],   k1h, m1,  0, 0, 0);
                    xa0 = MFMA16(qh[s],   k0l, xa0, 0, 0, 0);
                    xb0 = MFMA16(qlo4[s], k0h, xb0, 0, 0, 0);
                    xa1 = MFMA16(qh[s],   k1l, xa1, 0, 0, 0);
                    xb1 = MFMA16(qlo4[s], k1h, xb1, 0, 0, 0);
                }
                const bool full = (kt * 32 + 31 <= q0w);
                float p0[4], p1[4];
                float cs0 = 0.f, cs1 = 0.f;
                #pragma unroll
                for (int r = 0; r < 4; ++r) {
                    float e0 = fexp2((m0[r] + (xa0[r] + xb0[r])) * C);
                    float e1 = fexp2((m1[r] + (xa1[r] + xb1[r])) * C);
                    if (!full) {
                        const int q = q0w + lg * 4 + r;
                        if (kt * 32 + lr > q)      e0 = 0.f;
                        if (kt * 32 + 16 + lr > q) e1 = 0.f;
                    }
                    p0[r] = e0 * rl[r];
                    p1[r] = e1 * rl[r];
                    cs0 += p0[r];
                    cs1 += p1[r];
                }
                cs0 += __shfl_xor(cs0, 16); cs0 += __shfl_xor(cs0, 32);
                cs1 += __shfl_xor(cs1, 16); cs1 += __shfl_xor(cs1, 32);
                if (lg == 0) {
                    atomicAdd(&colsum[head * SEQ + kt * 32 + lr], (double)cs0);
                    atomicAdd(&colsum[head * SEQ + kt * 32 + 16 + lr], (double)cs1);
                }
                #pragma unroll
                for (int r = 0; r < 4; r += 2) {
                    const int row0 = (lg * 4 + r) * 40;
                    unsigned u0 = cvt_pk_bf16(p0[r], p0[r + 1]);
                    unsigned u1 = cvt_pk_bf16(p1[r], p1[r + 1]);
                    pl[row0 + lr]      = (unsigned short)u0;
                    pl[row0 + 40 + lr] = (unsigned short)(u0 >> 16);
                    pl[row0 + 16 + lr] = (unsigned short)u1;
                    pl[row0 + 56 + lr] = (unsigned short)(u1 >> 16);
                }
                const bf16x8 pa = *(const bf16x8*)(pl + lr * 40 + lg * 8);
                #pragma unroll
                for (int f = 0; f < 8; ++f) {
                    const bf16x8 vf = *(const bf16x8*)(vT + (size_t)(kvoff + f * 16 + lr) * SEQ
                                                       + kt * 32 + lg * 8);
                    oacc[f] = MFMA16(pa, vf, oacc[f], 0, 0, 0);
                }
            }
        }
        block_sync();
        #pragma unroll
        for (int f = 0; f < 8; ++f)
            #pragma unroll
            for (int r = 0; r < 4; ++r)
                obuf[(size_t)(q0w + lg * 4 + r) * HID + head * DHEAD + f * 16 + lr] =
                    f2bf(oacc[f][r]);
    }
}

__global__ __launch_bounds__(256) void attn_fused8(
    const unsigned short* __restrict__ qhi, const unsigned short* __restrict__ qlo,
    const unsigned short* __restrict__ khi, const unsigned short* __restrict__ klo,
    const unsigned short* __restrict__ vT,
    unsigned short* __restrict__ obuf, double* __restrict__ colsum)
{
    __shared__ unsigned short kbuf[4][2 * 4096];
    __shared__ unsigned short plds[4][16 * 40];
    const int head = blockIdx.x >> 4;
    const int pr = blockIdx.x & 15;
    const int tid = threadIdx.x;
    const int w = tid >> 6, lane = tid & 63;
    process_qblock8(head, pr, w, lane, qhi, qlo, khi, klo, vT, obuf, colsum,
                    &kbuf[0][0], &plds[w][0]);
    process_qblock8(head, 31 - pr, w, lane, qhi, qlo, khi, klo, vT, obuf, colsum,
                    &kbuf[0][0], &plds[w][0]);
}

// ---------------------------------------------------------------------------
// Top-k (204 of 1844) per head, exact jax.lax.top_k semantics (stable ties).
// ---------------------------------------------------------------------------
__global__ __launch_bounds__(256) void topk_kernel(const double* __restrict__ colsum,
                                                   float* __restrict__ outbuf)
{
    __shared__ float sc[SEL_N];
    __shared__ unsigned char fl[SEL_N];
    __shared__ int cnt;
    const int h = blockIdx.x;
    const int tid = threadIdx.x;
    for (int j = tid; j < SEL_N; j += 256) {
        sc[j] = (float)colsum[h * SEQ + j];
        fl[j] = 0;
    }
    __syncthreads();
    unsigned int cand = 0u;
    for (int b = 30; b >= 0; --b) {
        const unsigned int t = cand | (1u << b);
        const float tv = __uint_as_float(t);
        if (tid == 0) cnt = 0;
        __syncthreads();
        int local = 0;
        for (int j = tid; j < SEL_N; j += 256) local += (sc[j] >= tv) ? 1 : 0;
        atomicAdd(&cnt, local);
        __syncthreads();
        if (cnt >= HEAVY) cand = t;
        __syncthreads();
    }
    const float v204 = __uint_as_float(cand);
    if (tid == 0) cnt = 0;
    __syncthreads();
    int local = 0;
    for (int j = tid; j < SEL_N; j += 256) {
        if (sc[j] > v204) { fl[j] = 1; local++; }
    }
    atomicAdd(&cnt, local);
    __syncthreads();
    if (tid == 0) {
        int need = HEAVY - cnt;
        for (int j = 0; j < SEL_N && need > 0; ++j) {
            if (sc[j] == v204) { fl[j] = 1; --need; }
        }
    }
    __syncthreads();
    float* mask_out = outbuf + 8388608 + h * 2049;
    float* score_out = outbuf + 8388608 + NHEAD * 2049 + h * SEQ;
    for (int j = tid; j < 2049; j += 256) {
        float mv;
        if (j >= 1845) mv = 1.f;
        else if (j < SEL_N) mv = fl[j] ? 1.f : 0.f;
        else mv = 0.f;
        mask_out[j] = mv;
    }
    for (int j = tid; j < SEQ; j += 256) {
        const float cur = (float)colsum[h * SEQ + j];
        const float smv = (j >= SEL_N) ? 1.f : (fl[j] ? 1.f : 0.f);
        score_out[j] = cur * smv;
    }
}

// ---------------------------------------------------------------------------
extern "C" void kernel_launch(void* const* d_in, const int* in_sizes, int n_in,
                              void* d_out, int out_size, void* d_ws, size_t ws_size,
                              hipStream_t stream)
{
    const float* hidden = (const float*)d_in[0];
    const float* Wq = (const float*)d_in[2];
    const float* bq = (const float*)d_in[3];
    const float* Wk = (const float*)d_in[4];
    const float* bk = (const float*)d_in[5];
    const float* Wv = (const float*)d_in[6];
    const float* bv = (const float*)d_in[7];
    const float* Wo = (const float*)d_in[8];
    float* out = (float*)d_out;

    char* ws = (char*)d_ws;
    unsigned short* hs_hi = (unsigned short*)(ws);
    unsigned short* hs_lo = (unsigned short*)(ws + 16777216ull);
    unsigned short* wqT_hi = (unsigned short*)(ws + 33554432ull);
    unsigned short* wqT_lo = (unsigned short*)(ws + 67108864ull);
    unsigned short* wkT_hi = (unsigned short*)(ws + 100663296ull);
    unsigned short* wkT_lo = (unsigned short*)(ws + 109051904ull);
    unsigned short* wvT    = (unsigned short*)(ws + 117440512ull);
    unsigned short* q_hi   = (unsigned short*)(ws + 125829120ull);
    unsigned short* q_lo   = (unsigned short*)(ws + 142606336ull);
    unsigned short* k_hi   = (unsigned short*)(ws + 159383552ull);
    unsigned short* k_lo   = (unsigned short*)(ws + 163577856ull);
    unsigned short* v_bf   = (unsigned short*)(ws + 167772160ull);
    unsigned short* vT     = (unsigned short*)(ws + 171966464ull);
    unsigned short* o_bf   = (unsigned short*)(ws + 176160768ull);
    double* colsum         = (double*)(ws + 192937984ull);
    unsigned short* woT2   = (unsigned short*)(ws + 193462272ull);  // fresh 32MB
    unsigned short* woT_alias = wqT_hi;   // fallback: reuse after qkv_gemm

    const bool bigws = ws_size >= (193462272ull + 33554432ull);
    dim3 blk(256);

    prep_all<<<dim3(bigws ? 12352 : 8256), blk, 0, stream>>>(
        hidden, hs_hi, hs_lo, Wq, wqT_hi, wqT_lo, Wk, wkT_hi, wkT_lo, Wv, wvT,
        colsum, Wo, woT2);

    qkv_gemm<<<dim3(768), blk, 0, stream>>>(
        hs_hi, hs_lo, wqT_hi, wqT_lo, wkT_hi, wkT_lo, wvT,
        bq, bk, bv, q_hi, q_lo, k_hi, k_lo, v_bf);

    transpose_v<<<dim3(32, 16), blk, 0, stream>>>(v_bf, vT);
    attn_fused8<<<dim3(512), blk, 0, stream>>>(q_hi, q_lo, k_hi, k_lo, vT, o_bf, colsum);
    topk_kernel<<<dim3(32), blk, 0, stream>>>(colsum, out);

    const unsigned short* woT = woT2;
    if (!bigws) {
        wprep<false><<<dim3(64, 64), blk, 0, stream>>>(Wo, woT_alias, nullptr, HID, HID);
        woT = woT_alias;
    }
    gemm_wo<<<dim3(512), blk, 0, stream>>>(o_bf, woT, out, SEQ, HID, HID);
}

// Round 17
// 787.033 us; speedup vs baseline: 1.0061x; 1.0061x over previous
//
#include <hip/hip_runtime.h>
#include <stdint.h>

#define SEQ 2048
#define HID 4096
#define KVHID 1024
#define NHEAD 32
#define DHEAD 128
#define HEAVY 204
#define SEL_N 1844

typedef float f32x4 __attribute__((ext_vector_type(4)));
typedef __bf16 bf16x8 __attribute__((ext_vector_type(8)));

#define MFMA16 __builtin_amdgcn_mfma_f32_16x16x32_bf16

__device__ __forceinline__ unsigned short f2bf(float x) {
    unsigned int u = __float_as_uint(x);
    u = (u + 0x7fffu + ((u >> 16) & 1u)) >> 16;
    return (unsigned short)u;
}
__device__ __forceinline__ float bf2f(unsigned short s) {
    return __uint_as_float(((unsigned int)s) << 16);
}
__device__ __forceinline__ unsigned long long pack4(unsigned short a, unsigned short b,
                                                    unsigned short c, unsigned short d) {
    return (unsigned long long)a | ((unsigned long long)b << 16) |
           ((unsigned long long)c << 32) | ((unsigned long long)d << 48);
}
__device__ __forceinline__ float fexp2(float x) {
#if __has_builtin(__builtin_amdgcn_exp2f)
    return __builtin_amdgcn_exp2f(x);
#else
    float r; asm volatile("v_exp_f32 %0, %1\ns_nop 1" : "=v"(r) : "v"(x)); return r;
#endif
}
__device__ __forceinline__ unsigned cvt_pk_bf16(float lo, float hi) {
    unsigned r; asm("v_cvt_pk_bf16_f32 %0, %1, %2" : "=v"(r) : "v"(lo), "v"(hi)); return r;
}
__device__ __forceinline__ void gload_lds16(const unsigned short* g, unsigned short* l) {
    __builtin_amdgcn_global_load_lds(
        (const __attribute__((address_space(1))) void*)g,
        (__attribute__((address_space(3))) void*)l, 16, 0, 0);
}
__device__ __forceinline__ void block_sync() {
    asm volatile("" ::: "memory");
    __builtin_amdgcn_s_barrier();
    asm volatile("" ::: "memory");
}

// ---------------------------------------------------------------------------
// Merged prep kernel (r15 regions + colsum zeroing; NO Wo here — folding Wo
// into prep polluted L3 and cost qkv +157MB FETCH in r16).
//   [0,2048):    split hidden fp32 -> bf16 hi/lo
//   [2048,6144): Wq -> WqT hi/lo
//   [6144,7168): Wk -> WkT hi/lo
//   [7168,8192): Wv -> WvT (plain)
//   [8192,8256): zero colsum
// ---------------------------------------------------------------------------
template<bool SPLIT>
__device__ __forceinline__ void wprep_body(const float* __restrict__ W,
    unsigned short* __restrict__ Thi, unsigned short* __restrict__ Tlo,
    int K, int N, int bx, int by, float (*T)[65])
{
    const int k0 = by << 6, n0 = bx << 6;
    const int tid = threadIdx.x;
    const int c = tid & 63, r4 = tid >> 6;
    #pragma unroll
    for (int i = 0; i < 16; ++i)
        T[r4 + i * 4][c] = W[(size_t)(k0 + r4 + i * 4) * N + n0 + c];
    __syncthreads();
    #pragma unroll
    for (int i = 0; i < 16; ++i) {
        const int n = r4 + i * 4;
        const float x = T[c][n];
        const size_t o = (size_t)(n0 + n) * K + k0 + c;
        const unsigned short h = f2bf(x);
        Thi[o] = h;
        if constexpr (SPLIT) Tlo[o] = f2bf(x - bf2f(h));
    }
}

__global__ __launch_bounds__(256) void prep_all(
    const float* __restrict__ hidden,
    unsigned short* __restrict__ hs_hi, unsigned short* __restrict__ hs_lo,
    const float* __restrict__ Wq, unsigned short* __restrict__ wqT_hi,
    unsigned short* __restrict__ wqT_lo,
    const float* __restrict__ Wk, unsigned short* __restrict__ wkT_hi,
    unsigned short* __restrict__ wkT_lo,
    const float* __restrict__ Wv, unsigned short* __restrict__ wvT,
    double* __restrict__ colsum)
{
    __shared__ float T[64][65];
    const int bid = blockIdx.x;
    if (bid < 2048) {
        const int n4 = (SEQ * HID) / 4;
        int i = bid * 256 + threadIdx.x;
        for (; i < n4; i += 2048 * 256) {
            const float4 v = ((const float4*)hidden)[i];
            const unsigned short h0 = f2bf(v.x), h1 = f2bf(v.y),
                                 h2 = f2bf(v.z), h3 = f2bf(v.w);
            ((unsigned long long*)hs_hi)[i] = pack4(h0, h1, h2, h3);
            ((unsigned long long*)hs_lo)[i] =
                pack4(f2bf(v.x - bf2f(h0)), f2bf(v.y - bf2f(h1)),
                      f2bf(v.z - bf2f(h2)), f2bf(v.w - bf2f(h3)));
        }
    } else if (bid < 6144) {
        const int idx = bid - 2048;
        wprep_body<true>(Wq, wqT_hi, wqT_lo, HID, HID, idx & 63, idx >> 6, T);
    } else if (bid < 7168) {
        const int idx = bid - 6144;
        wprep_body<true>(Wk, wkT_hi, wkT_lo, HID, KVHID, idx & 15, idx >> 4, T);
    } else if (bid < 8192) {
        const int idx = bid - 7168;
        wprep_body<false>(Wv, wvT, nullptr, HID, KVHID, idx & 15, idx >> 4, T);
    } else {
        unsigned long long* p = (unsigned long long*)colsum;
        const int n = NHEAD * SEQ;
        for (int i = (bid - 8192) * 256 + threadIdx.x; i < n; i += 64 * 256)
            p[i] = 0ull;
    }
}

// ---------------------------------------------------------------------------
// Standalone wprep (Wo; runs after topk so woT stays L3-resident for gemm_wo).
// ---------------------------------------------------------------------------
template<bool SPLIT>
__global__ __launch_bounds__(256) void wprep(const float* __restrict__ W,
    unsigned short* __restrict__ Thi, unsigned short* __restrict__ Tlo, int K, int N)
{
    __shared__ float T[64][65];
    wprep_body<SPLIT>(W, Thi, Tlo, K, N, blockIdx.x, blockIdx.y, T);
}

// ---------------------------------------------------------------------------
// GEMM device body: SPLIT = 2-buffer double-barrier; non-SPLIT = 4-buffer
// rotation, 2-deep prefetch, one barrier per K-step. sm = 64KB.
// ---------------------------------------------------------------------------
template<bool SPLIT, int OUTMODE /*0=bf16,1=f32,2=bf16 hi+lo*/, bool BIAS>
__device__ __forceinline__ void gemm_body(
    const unsigned short* __restrict__ Ahi, const unsigned short* __restrict__ Alo,
    const unsigned short* __restrict__ Bhi, const unsigned short* __restrict__ Blo,
    const float* __restrict__ bias,
    void* __restrict__ C0, unsigned short* __restrict__ C1,
    int M, int N, int K, int mb, int nb, unsigned short* sm)
{
    constexpr int NT = SPLIT ? 4 : 2;
    const int tid = threadIdx.x;
    const int l = tid & 63, w = tid >> 6;
    const int lr = l & 15, lg = l >> 4;
    const int wm = (w >> 1) * 64, wn = (w & 1) * 64;
    const int m0 = mb * 128, n0 = nb * 128;

    const unsigned short* aH = Ahi + (size_t)m0 * K;
    const unsigned short* bH = Bhi + (size_t)n0 * K;
    const unsigned short* aL = SPLIT ? Alo + (size_t)m0 * K : nullptr;
    const unsigned short* bL = SPLIT ? Blo + (size_t)n0 * K : nullptr;

    const int s0_ = tid, s1_ = tid + 256;
    const int r0_ = s0_ >> 2, c0_ = (s0_ & 3) ^ (r0_ & 3);
    const int r1_ = s1_ >> 2, c1_ = (s1_ & 3) ^ (r1_ & 3);
    const size_t g0off = (size_t)r0_ * K + c0_ * 8;
    const size_t g1off = (size_t)r1_ * K + c1_ * 8;

#define GB_SLOT(buf, t) (sm + ((buf) * NT + (t)) * 4096)
#define GB_STAGE(buf, kk)                                                       \
    do {                                                                        \
        const int k0s = (kk) << 5;                                              \
        gload_lds16(aH + g0off + k0s, GB_SLOT(buf, 0) + s0_ * 8);               \
        gload_lds16(aH + g1off + k0s, GB_SLOT(buf, 0) + s1_ * 8);               \
        gload_lds16(bH + g0off + k0s, GB_SLOT(buf, 1) + s0_ * 8);               \
        gload_lds16(bH + g1off + k0s, GB_SLOT(buf, 1) + s1_ * 8);               \
        if constexpr (SPLIT) {                                                  \
            gload_lds16(aL + g0off + k0s, GB_SLOT(buf, 2) + s0_ * 8);           \
            gload_lds16(aL + g1off + k0s, GB_SLOT(buf, 2) + s1_ * 8);           \
            gload_lds16(bL + g0off + k0s, GB_SLOT(buf, 3) + s0_ * 8);           \
            gload_lds16(bL + g1off + k0s, GB_SLOT(buf, 3) + s1_ * 8);           \
        }                                                                       \
    } while (0)

#define GB_COMPUTE(BC)                                                          \
    do {                                                                        \
        bf16x8 ah[4], bh[4], al[4], bl[4];                                      \
        _Pragma("unroll")                                                       \
        for (int mi = 0; mi < 4; ++mi) {                                        \
            const int rr = wm + mi * 16 + lr;                                   \
            const int o = rr * 32 + ((lg ^ (rr & 3)) << 3);                     \
            ah[mi] = *(const bf16x8*)(GB_SLOT(BC, 0) + o);                      \
            if constexpr (SPLIT) al[mi] = *(const bf16x8*)(GB_SLOT(BC, 2) + o); \
        }                                                                       \
        _Pragma("unroll")                                                       \
        for (int ni = 0; ni < 4; ++ni) {                                        \
            const int rr = wn + ni * 16 + lr;                                   \
            const int o = rr * 32 + ((lg ^ (rr & 3)) << 3);                     \
            bh[ni] = *(const bf16x8*)(GB_SLOT(BC, 1) + o);                      \
            if constexpr (SPLIT) bl[ni] = *(const bf16x8*)(GB_SLOT(BC, 3) + o); \
        }                                                                       \
        __builtin_amdgcn_s_setprio(1);                                          \
        _Pragma("unroll")                                                       \
        for (int mi = 0; mi < 4; ++mi)                                          \
            _Pragma("unroll")                                                   \
            for (int ni = 0; ni < 4; ++ni) {                                    \
                acc[mi][ni] = MFMA16(ah[mi], bh[ni], acc[mi][ni], 0, 0, 0);     \
                if constexpr (SPLIT) {                                          \
                    acc[mi][ni] = MFMA16(ah[mi], bl[ni], acc[mi][ni], 0, 0, 0); \
                    acc[mi][ni] = MFMA16(al[mi], bh[ni], acc[mi][ni], 0, 0, 0); \
                }                                                               \
            }                                                                   \
        __builtin_amdgcn_s_setprio(0);                                          \
    } while (0)

    f32x4 acc[4][4];
    #pragma unroll
    for (int i = 0; i < 4; ++i)
        #pragma unroll
        for (int j = 0; j < 4; ++j) acc[i][j] = (f32x4){};

    const int nk = K >> 5;
    if constexpr (SPLIT) {
        GB_STAGE(0, 0);
        for (int kt = 0; kt < nk; ++kt) {
            if (kt + 1 < nk) {
                GB_STAGE((kt + 1) & 1, kt + 1);
                asm volatile("s_waitcnt vmcnt(8)" ::: "memory");
            } else {
                asm volatile("s_waitcnt vmcnt(0)" ::: "memory");
            }
            block_sync();
            GB_COMPUTE(kt & 1);
            block_sync();
        }
    } else {
        GB_STAGE(0, 0);
        GB_STAGE(1, 1);
        for (int kt = 0; kt < nk; ++kt) {
            if (kt + 2 < nk) {
                GB_STAGE((kt + 2) & 3, kt + 2);
                asm volatile("s_waitcnt vmcnt(8)" ::: "memory");
            } else if (kt + 1 < nk) {
                asm volatile("s_waitcnt vmcnt(4)" ::: "memory");
            } else {
                asm volatile("s_waitcnt vmcnt(0)" ::: "memory");
            }
            block_sync();
            GB_COMPUTE(kt & 3);
        }
    }
#undef GB_STAGE
#undef GB_COMPUTE
#undef GB_SLOT

    #pragma unroll
    for (int ni = 0; ni < 4; ++ni) {
        const int col = n0 + wn + ni * 16 + lr;
        float bv = 0.f;
        if constexpr (BIAS) bv = bias[col];
        #pragma unroll
        for (int mi = 0; mi < 4; ++mi) {
            #pragma unroll
            for (int r = 0; r < 4; ++r) {
                const int row = m0 + wm + mi * 16 + lg * 4 + r;
                const float x = acc[mi][ni][r] + bv;
                const size_t o = (size_t)row * N + col;
                if constexpr (OUTMODE == 1) {
                    ((float*)C0)[o] = x;
                } else if constexpr (OUTMODE == 0) {
                    ((unsigned short*)C0)[o] = f2bf(x);
                } else {
                    const unsigned short hi = f2bf(x);
                    ((unsigned short*)C0)[o] = hi;
                    C1[o] = f2bf(x - bf2f(hi));
                }
            }
        }
    }
}

// ---------------------------------------------------------------------------
// Merged Q/K/V projection (8x8 XCD rectangle for Q region).
// ---------------------------------------------------------------------------
__global__ __launch_bounds__(256) void qkv_gemm(
    const unsigned short* __restrict__ hs_hi, const unsigned short* __restrict__ hs_lo,
    const unsigned short* __restrict__ wqT_hi, const unsigned short* __restrict__ wqT_lo,
    const unsigned short* __restrict__ wkT_hi, const unsigned short* __restrict__ wkT_lo,
    const unsigned short* __restrict__ wvT,
    const float* __restrict__ bq, const float* __restrict__ bk, const float* __restrict__ bv,
    unsigned short* __restrict__ q_hi, unsigned short* __restrict__ q_lo,
    unsigned short* __restrict__ k_hi, unsigned short* __restrict__ k_lo,
    unsigned short* __restrict__ v_bf)
{
    __shared__ unsigned short sm[8 * 4096];   // 64KB
    const int bid = blockIdx.x;
    if (bid < 512) {
        const int r = bid & 7, rid = bid >> 3;
        const int mb = ((r >> 2) << 3) + (rid >> 3);
        const int nb = ((r & 3) << 3) + (rid & 7);
        gemm_body<true, 2, true>(hs_hi, hs_lo, wqT_hi, wqT_lo, bq, q_hi, q_lo,
                                 SEQ, HID, HID, mb, nb, sm);
    } else if (bid < 640) {
        const int idx = bid - 512;
        gemm_body<true, 2, true>(hs_hi, hs_lo, wkT_hi, wkT_lo, bk, k_hi, k_lo,
                                 SEQ, KVHID, HID, idx >> 3, idx & 7, sm);
    } else {
        const int idx = bid - 640;
        gemm_body<false, 0, true>(hs_hi, nullptr, wvT, nullptr, bv, v_bf, nullptr,
                                  SEQ, KVHID, HID, idx >> 3, idx & 7, sm);
    }
}

// ---------------------------------------------------------------------------
// Wo GEMM: plain bf16, f32 out, 8x8 XCD rectangle swizzle (512 blocks).
// ---------------------------------------------------------------------------
__global__ __launch_bounds__(256) void gemm_wo(
    const unsigned short* __restrict__ A, const unsigned short* __restrict__ B,
    float* __restrict__ C, int M, int N, int K)
{
    __shared__ unsigned short sm[8 * 4096];
    const int bid = blockIdx.x;
    const int r = bid & 7, rid = bid >> 3;
    const int mb = ((r >> 2) << 3) + (rid >> 3);
    const int nb = ((r & 3) << 3) + (rid & 7);
    gemm_body<false, 1, false>(A, nullptr, B, nullptr, nullptr, C, nullptr,
                               M, N, K, mb, nb, sm);
}

// ---------------------------------------------------------------------------
// V transpose: v[2048][1024] -> vT[1024][2048] (bf16).
// ---------------------------------------------------------------------------
__global__ __launch_bounds__(256) void transpose_v(const unsigned short* __restrict__ v,
                                                   unsigned short* __restrict__ vt)
{
    __shared__ unsigned short T[64][65];
    const int r0 = blockIdx.x * 64;
    const int c0 = blockIdx.y * 64;
    const int tid = threadIdx.x;
    const int cc = tid & 63, rr = tid >> 6;
    #pragma unroll
    for (int i = 0; i < 16; ++i)
        T[rr + i * 4][cc] = v[(size_t)(r0 + rr + i * 4) * KVHID + c0 + cc];
    __syncthreads();
    #pragma unroll
    for (int i = 0; i < 16; ++i) {
        const int oc = rr + i * 4;
        vt[(size_t)(c0 + oc) * SEQ + r0 + cc] = T[cc][oc];
    }
}

// ---------------------------------------------------------------------------
// Fused attention v8 (unchanged).
// ---------------------------------------------------------------------------
__device__ __forceinline__ void stage_tile(
    const unsigned short* __restrict__ khi, const unsigned short* __restrict__ klo,
    unsigned short* kb, int kt, int kvoff, int w, int lane)
{
    const unsigned short* src = (w >> 1) ? klo : khi;
    unsigned short* dst = kb + (w >> 1) * 4096 + (w & 1) * 2048;
    const int lsub = lane >> 4;
    const int lbyte = (lane & 15) * 16;
    #pragma unroll
    for (int j = 0; j < 4; ++j) {
        const int row = (w & 1) * 16 + j * 4 + lsub;
        const int soff = (lbyte ^ ((row & 7) << 4)) >> 1;
        const unsigned short* g = src + (size_t)(kt * 32 + row) * KVHID + kvoff + soff;
        gload_lds16(g, dst + j * 512);
    }
}

__device__ __forceinline__ void process_qblock8(
    int head, int qb, int w, int lane,
    const unsigned short* __restrict__ qhi, const unsigned short* __restrict__ qlo,
    const unsigned short* __restrict__ khi, const unsigned short* __restrict__ klo,
    const unsigned short* __restrict__ vT,
    unsigned short* __restrict__ obuf, double* __restrict__ colsum,
    unsigned short* kbuf /*[4][8192]*/, unsigned short* pl)
{
    const int lr = lane & 15, lg = lane >> 4;
    const int kvoff = (head >> 2) * DHEAD;
    const int q0w = qb * 64 + w * 16;
    const int NT = 2 * qb + 2;
    const int wnt = ((q0w + 15) >> 5) + 1;
    const float C = 0.08838834764831845f * 1.44269504088896340f;

    bf16x8 qh[4], qlo4[4];
    {
        const size_t qbase = (size_t)(q0w + lr) * HID + head * DHEAD + lg * 8;
        #pragma unroll
        for (int s = 0; s < 4; ++s) {
            qh[s]   = *(const bf16x8*)(qhi + qbase + s * 32);
            qlo4[s] = *(const bf16x8*)(qlo + qbase + s * 32);
        }
    }
    const int swz = (lr & 7) << 3;

    float rl[4];
    // ================= sweep A: row sums =================
    {
        float lp[4] = {0.f, 0.f, 0.f, 0.f};
        stage_tile(khi, klo, kbuf, 0, kvoff, w, lane);
        stage_tile(khi, klo, kbuf + 8192, 1, kvoff, w, lane);
        for (int kt = 0; kt < NT; ++kt) {
            if (kt + 2 < NT) {
                stage_tile(khi, klo, kbuf + ((kt + 2) & 3) * 8192, kt + 2, kvoff, w, lane);
                asm volatile("s_waitcnt vmcnt(8)" ::: "memory");
            } else if (kt + 1 < NT) {
                asm volatile("s_waitcnt vmcnt(4)" ::: "memory");
            } else {
                asm volatile("s_waitcnt vmcnt(0)" ::: "memory");
            }
            block_sync();
            const unsigned short* kb = kbuf + (kt & 3) * 8192;
            if (kt < wnt) {
                f32x4 m0 = {}, m1 = {}, xa0 = {}, xb0 = {}, xa1 = {}, xb1 = {};
                #pragma unroll
                for (int s = 0; s < 4; ++s) {
                    const int d = s * 32 + lg * 8;
                    const bf16x8 k0h = *(const bf16x8*)(kb + (lr * 128 + (d ^ swz)));
                    const bf16x8 k1h = *(const bf16x8*)(kb + ((16 + lr) * 128 + (d ^ swz)));
                    const bf16x8 k0l = *(const bf16x8*)(kb + 4096 + lr * 128 + (d ^ swz));
                    const bf16x8 k1l = *(const bf16x8*)(kb + 4096 + (16 + lr) * 128 + (d ^ swz));
                    m0  = MFMA16(qh[s],   k0h, m0,  0, 0, 0);
                    m1  = MFMA16(qh[s],   k1h, m1,  0, 0, 0);
                    xa0 = MFMA16(qh[s],   k0l, xa0, 0, 0, 0);
                    xb0 = MFMA16(qlo4[s], k0h, xb0, 0, 0, 0);
                    xa1 = MFMA16(qh[s],   k1l, xa1, 0, 0, 0);
                    xb1 = MFMA16(qlo4[s], k1h, xb1, 0, 0, 0);
                }
                const bool full = (kt * 32 + 31 <= q0w);
                #pragma unroll
                for (int r = 0; r < 4; ++r) {
                    float e0 = fexp2((m0[r] + (xa0[r] + xb0[r])) * C);
                    float e1 = fexp2((m1[r] + (xa1[r] + xb1[r])) * C);
                    if (!full) {
                        const int q = q0w + lg * 4 + r;
                        if (kt * 32 + lr > q)      e0 = 0.f;
                        if (kt * 32 + 16 + lr > q) e1 = 0.f;
                    }
                    lp[r] += e0 + e1;
                }
            }
        }
        block_sync();
        #pragma unroll
        for (int r = 0; r < 4; ++r) {
            float v = lp[r];
            v += __shfl_xor(v, 1);
            v += __shfl_xor(v, 2);
            v += __shfl_xor(v, 4);
            v += __shfl_xor(v, 8);
            rl[r] = 1.0f / v;
        }
    }
    // ============ sweep B: p, colsum, PV =================
    {
        f32x4 oacc[8];
        #pragma unroll
        for (int f = 0; f < 8; ++f) oacc[f] = (f32x4){};
        stage_tile(khi, klo, kbuf, 0, kvoff, w, lane);
        stage_tile(khi, klo, kbuf + 8192, 1, kvoff, w, lane);
        for (int kt = 0; kt < NT; ++kt) {
            if (kt + 2 < NT) {
                stage_tile(khi, klo, kbuf + ((kt + 2) & 3) * 8192, kt + 2, kvoff, w, lane);
                asm volatile("s_waitcnt vmcnt(8)" ::: "memory");
            } else if (kt + 1 < NT) {
                asm volatile("s_waitcnt vmcnt(4)" ::: "memory");
            } else {
                asm volatile("s_waitcnt vmcnt(0)" ::: "memory");
            }
            block_sync();
            const unsigned short* kb = kbuf + (kt & 3) * 8192;
            if (kt < wnt) {
                f32x4 m0 = {}, m1 = {}, xa0 = {}, xb0 = {}, xa1 = {}, xb1 = {};
                #pragma unroll
                for (int s = 0; s < 4; ++s) {
                    const int d = s * 32 + lg * 8;
                    const bf16x8 k0h = *(const bf16x8*)(kb + (lr * 128 + (d ^ swz)));
                    const bf16x8 k1h = *(const bf16x8*)(kb + ((16 + lr) * 128 + (d ^ swz)));
                    const bf16x8 k0l = *(const bf16x8*)(kb + 4096 + lr * 128 + (d ^ swz));
                    const bf16x8 k1l = *(const bf16x8*)(kb + 4096 + (16 + lr) * 128 + (d ^ swz));
                    m0  = MFMA16(qh[s],   k0h, m0,  0, 0, 0);
                    m1  = MFMA16(qh[s],   k1h, m1,  0, 0, 0);
                    xa0 = MFMA16(qh[s],   k0l, xa0, 0, 0, 0);
                    xb0 = MFMA16(qlo4[s], k0h, xb0, 0, 0, 0);
                    xa1 = MFMA16(qh[s],   k1l, xa1, 0, 0, 0);
                    xb1 = MFMA16(qlo4[s], k1h, xb1, 0, 0, 0);
                }
                const bool full = (kt * 32 + 31 <= q0w);
                float p0[4], p1[4];
                float cs0 = 0.f, cs1 = 0.f;
                #pragma unroll
                for (int r = 0; r < 4; ++r) {
                    float e0 = fexp2((m0[r] + (xa0[r] + xb0[r])) * C);
                    float e1 = fexp2((m1[r] + (xa1[r] + xb1[r])) * C);
                    if (!full) {
                        const int q = q0w + lg * 4 + r;
                        if (kt * 32 + lr > q)      e0 = 0.f;
                        if (kt * 32 + 16 + lr > q) e1 = 0.f;
                    }
                    p0[r] = e0 * rl[r];
                    p1[r] = e1 * rl[r];
                    cs0 += p0[r];
                    cs1 += p1[r];
                }
                cs0 += __shfl_xor(cs0, 16); cs0 += __shfl_xor(cs0, 32);
                cs1 += __shfl_xor(cs1, 16); cs1 += __shfl_xor(cs1, 32);
                if (lg == 0) {
                    atomicAdd(&colsum[head * SEQ + kt * 32 + lr], (double)cs0);
                    atomicAdd(&colsum[head * SEQ + kt * 32 + 16 + lr], (double)cs1);
                }
                #pragma unroll
                for (int r = 0; r < 4; r += 2) {
                    const int row0 = (lg * 4 + r) * 40;
                    unsigned u0 = cvt_pk_bf16(p0[r], p0[r + 1]);
                    unsigned u1 = cvt_pk_bf16(p1[r], p1[r + 1]);
                    pl[row0 + lr]      = (unsigned short)u0;
                    pl[row0 + 40 + lr] = (unsigned short)(u0 >> 16);
                    pl[row0 + 16 + lr] = (unsigned short)u1;
                    pl[row0 + 56 + lr] = (unsigned short)(u1 >> 16);
                }
                const bf16x8 pa = *(const bf16x8*)(pl + lr * 40 + lg * 8);
                #pragma unroll
                for (int f = 0; f < 8; ++f) {
                    const bf16x8 vf = *(const bf16x8*)(vT + (size_t)(kvoff + f * 16 + lr) * SEQ
                                                       + kt * 32 + lg * 8);
                    oacc[f] = MFMA16(pa, vf, oacc[f], 0, 0, 0);
                }
            }
        }
        block_sync();
        #pragma unroll
        for (int f = 0; f < 8; ++f)
            #pragma unroll
            for (int r = 0; r < 4; ++r)
                obuf[(size_t)(q0w + lg * 4 + r) * HID + head * DHEAD + f * 16 + lr] =
                    f2bf(oacc[f][r]);
    }
}

__global__ __launch_bounds__(256) void attn_fused8(
    const unsigned short* __restrict__ qhi, const unsigned short* __restrict__ qlo,
    const unsigned short* __restrict__ khi, const unsigned short* __restrict__ klo,
    const unsigned short* __restrict__ vT,
    unsigned short* __restrict__ obuf, double* __restrict__ colsum)
{
    __shared__ unsigned short kbuf[4][2 * 4096];
    __shared__ unsigned short plds[4][16 * 40];
    const int head = blockIdx.x >> 4;
    const int pr = blockIdx.x & 15;
    const int tid = threadIdx.x;
    const int w = tid >> 6, lane = tid & 63;
    process_qblock8(head, pr, w, lane, qhi, qlo, khi, klo, vT, obuf, colsum,
                    &kbuf[0][0], &plds[w][0]);
    process_qblock8(head, 31 - pr, w, lane, qhi, qlo, khi, klo, vT, obuf, colsum,
                    &kbuf[0][0], &plds[w][0]);
}

// ---------------------------------------------------------------------------
// Top-k (204 of 1844) per head, exact jax.lax.top_k semantics (stable ties).
// ---------------------------------------------------------------------------
__global__ __launch_bounds__(256) void topk_kernel(const double* __restrict__ colsum,
                                                   float* __restrict__ outbuf)
{
    __shared__ float sc[SEL_N];
    __shared__ unsigned char fl[SEL_N];
    __shared__ int cnt;
    const int h = blockIdx.x;
    const int tid = threadIdx.x;
    for (int j = tid; j < SEL_N; j += 256) {
        sc[j] = (float)colsum[h * SEQ + j];
        fl[j] = 0;
    }
    __syncthreads();
    unsigned int cand = 0u;
    for (int b = 30; b >= 0; --b) {
        const unsigned int t = cand | (1u << b);
        const float tv = __uint_as_float(t);
        if (tid == 0) cnt = 0;
        __syncthreads();
        int local = 0;
        for (int j = tid; j < SEL_N; j += 256) local += (sc[j] >= tv) ? 1 : 0;
        atomicAdd(&cnt, local);
        __syncthreads();
        if (cnt >= HEAVY) cand = t;
        __syncthreads();
    }
    const float v204 = __uint_as_float(cand);
    if (tid == 0) cnt = 0;
    __syncthreads();
    int local = 0;
    for (int j = tid; j < SEL_N; j += 256) {
        if (sc[j] > v204) { fl[j] = 1; local++; }
    }
    atomicAdd(&cnt, local);
    __syncthreads();
    if (tid == 0) {
        int need = HEAVY - cnt;
        for (int j = 0; j < SEL_N && need > 0; ++j) {
            if (sc[j] == v204) { fl[j] = 1; --need; }
        }
    }
    __syncthreads();
    float* mask_out = outbuf + 8388608 + h * 2049;
    float* score_out = outbuf + 8388608 + NHEAD * 2049 + h * SEQ;
    for (int j = tid; j < 2049; j += 256) {
        float mv;
        if (j >= 1845) mv = 1.f;
        else if (j < SEL_N) mv = fl[j] ? 1.f : 0.f;
        else mv = 0.f;
        mask_out[j] = mv;
    }
    for (int j = tid; j < SEQ; j += 256) {
        const float cur = (float)colsum[h * SEQ + j];
        const float smv = (j >= SEL_N) ? 1.f : (fl[j] ? 1.f : 0.f);
        score_out[j] = cur * smv;
    }
}

// ---------------------------------------------------------------------------
extern "C" void kernel_launch(void* const* d_in, const int* in_sizes, int n_in,
                              void* d_out, int out_size, void* d_ws, size_t ws_size,
                              hipStream_t stream)
{
    const float* hidden = (const float*)d_in[0];
    const float* Wq = (const float*)d_in[2];
    const float* bq = (const float*)d_in[3];
    const float* Wk = (const float*)d_in[4];
    const float* bk = (const float*)d_in[5];
    const float* Wv = (const float*)d_in[6];
    const float* bv = (const float*)d_in[7];
    const float* Wo = (const float*)d_in[8];
    float* out = (float*)d_out;

    char* ws = (char*)d_ws;
    unsigned short* hs_hi = (unsigned short*)(ws);
    unsigned short* hs_lo = (unsigned short*)(ws + 16777216ull);
    unsigned short* wqT_hi = (unsigned short*)(ws + 33554432ull);
    unsigned short* wqT_lo = (unsigned short*)(ws + 67108864ull);
    unsigned short* wkT_hi = (unsigned short*)(ws + 100663296ull);
    unsigned short* wkT_lo = (unsigned short*)(ws + 109051904ull);
    unsigned short* wvT    = (unsigned short*)(ws + 117440512ull);
    unsigned short* q_hi   = (unsigned short*)(ws + 125829120ull);
    unsigned short* q_lo   = (unsigned short*)(ws + 142606336ull);
    unsigned short* k_hi   = (unsigned short*)(ws + 159383552ull);
    unsigned short* k_lo   = (unsigned short*)(ws + 163577856ull);
    unsigned short* v_bf   = (unsigned short*)(ws + 167772160ull);
    unsigned short* vT     = (unsigned short*)(ws + 171966464ull);
    unsigned short* o_bf   = (unsigned short*)(ws + 176160768ull);
    double* colsum         = (double*)(ws + 192937984ull);
    unsigned short* woT    = wqT_hi;   // reuse after qkv_gemm (stream-ordered)

    dim3 blk(256);
    prep_all<<<dim3(8256), blk, 0, stream>>>(
        hidden, hs_hi, hs_lo, Wq, wqT_hi, wqT_lo, Wk, wkT_hi, wkT_lo, Wv, wvT, colsum);

    qkv_gemm<<<dim3(768), blk, 0, stream>>>(
        hs_hi, hs_lo, wqT_hi, wqT_lo, wkT_hi, wkT_lo, wvT,
        bq, bk, bv, q_hi, q_lo, k_hi, k_lo, v_bf);

    transpose_v<<<dim3(32, 16), blk, 0, stream>>>(v_bf, vT);
    attn_fused8<<<dim3(512), blk, 0, stream>>>(q_hi, q_lo, k_hi, k_lo, vT, o_bf, colsum);
    topk_kernel<<<dim3(32), blk, 0, stream>>>(colsum, out);

    wprep<false><<<dim3(64, 64), blk, 0, stream>>>(Wo, woT, nullptr, HID, HID);
    gemm_wo<<<dim3(512), blk, 0, stream>>>(o_bf, woT, out, SEQ, HID, HID);
}